// Round 6
// baseline (138.125 us; speedup 1.0000x reference)
//
#include <hip/hip_runtime.h>
#include <cmath>

#define BB   512
#define NSV  128
#define NTRK 512
#define KK   8
#define HH   16
#define TPB  512
#define TST  36            // T row stride in shorts (72B): [thi 16][tlo 16][htsq f32]  gcd(18,32)=2
#define SST  36            // S row stride in shorts (72B): [shi 16][slo 16][pad]
#define PSTR 20            // proj stride (f32), multiple of 4 for b128 slices

typedef float    f32x4  __attribute__((ext_vector_type(4)));
typedef short    bf16x8 __attribute__((ext_vector_type(8)));
typedef unsigned u32x4  __attribute__((ext_vector_type(4)));

__device__ __forceinline__ float elu_f(float x) {
    float e = __builtin_amdgcn_exp2f(x * 1.44269504088896341f) - 1.0f;
    return x > 0.0f ? x : e;
}
__device__ __forceinline__ unsigned umin_u(unsigned a, unsigned b) { return a < b ? a : b; }
__device__ __forceinline__ unsigned umax_u(unsigned a, unsigned b) { return a > b ? a : b; }
__device__ __forceinline__ unsigned med3u(unsigned a, unsigned b, unsigned c) {
    unsigned d;
    asm("v_med3_u32 %0, %1, %2, %3" : "=v"(d) : "v"(a), "v"(b), "v"(c));
    return d;
}
__device__ __forceinline__ bf16x8 mk_bf8(uint2 a, uint2 b) {
    u32x4 u; u.x = a.x; u.y = a.y; u.z = b.x; u.w = b.y;
    return __builtin_bit_cast(bf16x8, u);
}
__device__ __forceinline__ float uasf(unsigned u) { return __uint_as_float(u); }

// One block = one batch. 512 threads, 8 waves.
// Phase A: per-thread track MLP -> split-bf16 [thi|tlo]+htsq rows (stride 36
//          shorts, gcd-2 banks); threads 0-127: SV MLP -> S rows + hsq + proj.
// Phase B: per wave, hoist all 16 SV MFMA fragments (hi/lo x 8 sv-tiles) into
//          regs ONCE (tile-invariant; R5 re-read them 4x). Per track-tile:
//          16x mfma_f32_16x16x32_bf16 (split-bf16 exact dot), med3-chain top-8
//          per lane, 2-stage shfl_xor bitonic merge -> ALL 4 g-lanes hold the
//          same top-8 SET (min-merge is set-symmetric). Epilogue folded in:
//          lane g gathers proj[row][4g..4g+3] (4 lanes cover the row), computes
//          its 4-dim slice of mx.Wo + tf.u, 2x shfl_xor add -> sigmoid.
//          knnS + phase C + one barrier deleted. LDS 80.9 -> ~57 KB.
// [R5 errata: A-frags re-read per tile (64 redundant ds_reads/wave); gcd-4
//  strides -> 2.34M bank-conflict cycles; serialized phase C.]
__global__ __launch_bounds__(TPB, 4) void fused_all(
    const float* __restrict__ x_sv, const float* __restrict__ x_trk,
    const float* __restrict__ W1s, const float* __restrict__ b1s,
    const float* __restrict__ W2s, const float* __restrict__ b2s,
    const float* __restrict__ W1t, const float* __restrict__ b1t,
    const float* __restrict__ W2t, const float* __restrict__ b2t,
    const float* __restrict__ We,  const float* __restrict__ be,
    const float* __restrict__ Wo,  const float* __restrict__ bo,
    float* __restrict__ out)
{
    __shared__ __align__(16) short Tsh[NTRK * TST];   // 36.9 KB
    __shared__ __align__(16) short Ssh[NSV * SST];    // 9.2 KB
    __shared__ __align__(16) float hsqS[NSV];         // 0.5 KB
    __shared__ __align__(16) float proj[NSV][PSTR];   // 10.2 KB
    __shared__ __align__(16) float ucS[HH + 1];
    __shared__ __align__(16) float WoS[HH];
    __shared__ float sred[TPB / 64];

    const int b = blockIdx.x, tid = threadIdx.x;

    // ================= phase A =================
    {
        const float* xp = x_trk + (size_t)(b * NTRK + tid) * 8;
        float x[8];
        *(float4*)&x[0] = *(const float4*)&xp[0];
        *(float4*)&x[4] = *(const float4*)&xp[4];
        float hb[HH];
        #pragma unroll
        for (int h = 0; h < HH; ++h) {
            float a = b1t[h];
            #pragma unroll
            for (int i = 0; i < 8; ++i) a += x[i] * W1t[i * HH + h];
            hb[h] = elu_f(a);
        }
        float tf[HH], sq = 0.0f;
        #pragma unroll
        for (int h2 = 0; h2 < HH; ++h2) {
            float a = b2t[h2];
            #pragma unroll
            for (int h = 0; h < HH; ++h) a += hb[h] * W2t[h * HH + h2];
            tf[h2] = a;
            sq += a * a;
        }
        unsigned hw[8], lw[8];
        #pragma unroll
        for (int j = 0; j < 8; ++j) {
            float f0 = tf[2 * j], f1 = tf[2 * j + 1];
            unsigned u0 = __float_as_uint(f0) & 0xFFFF0000u;
            unsigned u1 = __float_as_uint(f1) & 0xFFFF0000u;
            hw[j] = (u0 >> 16) | u1;
            float r0 = f0 - uasf(u0);
            float r1 = f1 - uasf(u1);
            lw[j] = (__float_as_uint(r0) >> 16) | (__float_as_uint(r1) & 0xFFFF0000u);
        }
        unsigned* tr = (unsigned*)&Tsh[tid * TST];
        *(uint2*)(tr + 0)  = make_uint2(hw[0], hw[1]);
        *(uint2*)(tr + 2)  = make_uint2(hw[2], hw[3]);
        *(uint2*)(tr + 4)  = make_uint2(hw[4], hw[5]);
        *(uint2*)(tr + 6)  = make_uint2(hw[6], hw[7]);
        *(uint2*)(tr + 8)  = make_uint2(lw[0], lw[1]);
        *(uint2*)(tr + 10) = make_uint2(lw[2], lw[3]);
        *(uint2*)(tr + 12) = make_uint2(lw[4], lw[5]);
        *(uint2*)(tr + 14) = make_uint2(lw[6], lw[7]);
        ((float*)tr)[16] = 0.5f * sq;
    }

    if (tid < NSV) {
        const float* xp = x_sv + (size_t)(b * NSV + tid) * 2;
        float x0 = xp[0], x1 = xp[1];
        float hb[HH];
        #pragma unroll
        for (int h = 0; h < HH; ++h)
            hb[h] = elu_f(x0 * W1s[h] + x1 * W1s[HH + h] + b1s[h]);
        float o[HH], sq = 0.0f;
        #pragma unroll
        for (int h2 = 0; h2 < HH; ++h2) {
            float a = b2s[h2];
            #pragma unroll
            for (int h = 0; h < HH; ++h) a += hb[h] * W2s[h * HH + h2];
            o[h2] = a;
            sq += a * a;
        }
        unsigned hw[8], lw[8];
        #pragma unroll
        for (int j = 0; j < 8; ++j) {
            float f0 = o[2 * j], f1 = o[2 * j + 1];
            unsigned u0 = __float_as_uint(f0) & 0xFFFF0000u;
            unsigned u1 = __float_as_uint(f1) & 0xFFFF0000u;
            hw[j] = (u0 >> 16) | u1;
            float r0 = f0 - uasf(u0);
            float r1 = f1 - uasf(u1);
            lw[j] = (__float_as_uint(r0) >> 16) | (__float_as_uint(r1) & 0xFFFF0000u);
        }
        unsigned* sr = (unsigned*)&Ssh[tid * SST];
        *(uint2*)(sr + 0)  = make_uint2(hw[0], hw[1]);
        *(uint2*)(sr + 2)  = make_uint2(hw[2], hw[3]);
        *(uint2*)(sr + 4)  = make_uint2(hw[4], hw[5]);
        *(uint2*)(sr + 6)  = make_uint2(hw[6], hw[7]);
        *(uint2*)(sr + 8)  = make_uint2(lw[0], lw[1]);
        *(uint2*)(sr + 10) = make_uint2(lw[2], lw[3]);
        *(uint2*)(sr + 12) = make_uint2(lw[4], lw[5]);
        *(uint2*)(sr + 14) = make_uint2(lw[6], lw[7]);
        hsqS[tid] = 0.5f * sq;
        #pragma unroll
        for (int h = 0; h < HH; ++h) {
            float a = 0.0f;
            #pragma unroll
            for (int j = 0; j < HH; ++j) a += o[j] * We[(HH + j) * HH + h];
            proj[tid][h] = a;
        }
    } else if (tid < NSV + HH) {
        int j = tid - NSV;
        float a = 0.0f;
        #pragma unroll
        for (int h = 0; h < HH; ++h)
            a += (We[j * HH + h] - We[(HH + j) * HH + h]) * Wo[h];
        ucS[j] = a;
    } else if (tid < NSV + 2 * HH) {
        int j = tid - NSV - HH;
        WoS[j] = Wo[j];
    } else if (tid == NSV + 2 * HH) {
        float a = bo[0];
        #pragma unroll
        for (int h = 0; h < HH; ++h) a += be[h] * Wo[h];
        ucS[HH] = a;
    }

    __syncthreads();

    // ================= phase B: MFMA + top-8 + fused epilogue =================
    float wsum = 0.0f;
    {
        const int lane = tid & 63;
        const int w    = tid >> 6;
        const int c    = lane & 15;
        const int g    = lane >> 4;
        const int g4   = g << 2;
        const int gd   = (g & 1) << 2;   // A-frag dword offset (dup-K)

        // hoist SV fragments (tile-invariant): 16 x bf16x8 = 64 VGPR
        bf16x8 sfh[8], sfl[8];
        #pragma unroll
        for (int ss = 0; ss < 8; ++ss) {
            const unsigned* sp = (const unsigned*)&Ssh[(ss * 16 + c) * SST];
            uint2 h0 = *(const uint2*)(sp + gd);
            uint2 h1 = *(const uint2*)(sp + gd + 2);
            uint2 l0 = *(const uint2*)(sp + 8 + gd);
            uint2 l1 = *(const uint2*)(sp + 8 + gd + 2);
            sfh[ss] = mk_bf8(h0, h1);
            sfl[ss] = mk_bf8(l0, l1);
        }

        #pragma unroll
        for (int i = 0; i < 4; ++i) {
            const int trk = (w + 8 * i) * 16 + c;
            const unsigned* tp = (const unsigned*)&Tsh[trk * TST];
            uint2 bq0 = *(const uint2*)(tp + g * 4);
            uint2 bq1 = *(const uint2*)(tp + g * 4 + 2);
            bf16x8 bfrag = mk_bf8(bq0, bq1);
            const float htsq = ((const float*)tp)[16];

            unsigned k0 = ~0u, k1 = ~0u, k2 = ~0u, k3 = ~0u,
                     k4 = ~0u, k5 = ~0u, k6 = ~0u, k7 = ~0u;
            #define CHAIN(v)                                               \
                do {                                                       \
                    unsigned nk0 = umin_u(v, k0);                          \
                    unsigned nk1 = med3u(v, k0, k1);                       \
                    unsigned nk2 = med3u(v, k1, k2);                       \
                    unsigned nk3 = med3u(v, k2, k3);                       \
                    unsigned nk4 = med3u(v, k3, k4);                       \
                    unsigned nk5 = med3u(v, k4, k5);                       \
                    unsigned nk6 = med3u(v, k5, k6);                       \
                    unsigned nk7 = med3u(v, k6, k7);                       \
                    k0 = nk0; k1 = nk1; k2 = nk2; k3 = nk3;                \
                    k4 = nk4; k5 = nk5; k6 = nk6; k7 = nk7;                \
                } while (0)
            #define CONSUME(accv, ssid)                                    \
                do {                                                       \
                    f32x4 hq = *(const f32x4*)&hsqS[(ssid) * 16 + g4];     \
                    float e0 = fmaxf((htsq - accv.x) + hq.x, 0.0f);        \
                    float e1 = fmaxf((htsq - accv.y) + hq.y, 0.0f);        \
                    float e2 = fmaxf((htsq - accv.z) + hq.z, 0.0f);        \
                    float e3 = fmaxf((htsq - accv.w) + hq.w, 0.0f);        \
                    unsigned v0 = (__float_as_uint(e0) & 0xFFFFFF80u) | (unsigned)((ssid) * 16 + g4 + 0); \
                    CHAIN(v0);                                             \
                    unsigned v1 = (__float_as_uint(e1) & 0xFFFFFF80u) | (unsigned)((ssid) * 16 + g4 + 1); \
                    CHAIN(v1);                                             \
                    unsigned v2 = (__float_as_uint(e2) & 0xFFFFFF80u) | (unsigned)((ssid) * 16 + g4 + 2); \
                    CHAIN(v2);                                             \
                    unsigned v3 = (__float_as_uint(e3) & 0xFFFFFF80u) | (unsigned)((ssid) * 16 + g4 + 3); \
                    CHAIN(v3);                                             \
                } while (0)

            #pragma unroll
            for (int half = 0; half < 2; ++half) {
                const int s0 = half * 4;
                f32x4 a0 = {0.f, 0.f, 0.f, 0.f}, a1 = a0, a2 = a0, a3 = a0;
                a0 = __builtin_amdgcn_mfma_f32_16x16x32_bf16(sfh[s0 + 0], bfrag, a0, 0, 0, 0);
                a1 = __builtin_amdgcn_mfma_f32_16x16x32_bf16(sfh[s0 + 1], bfrag, a1, 0, 0, 0);
                a2 = __builtin_amdgcn_mfma_f32_16x16x32_bf16(sfh[s0 + 2], bfrag, a2, 0, 0, 0);
                a3 = __builtin_amdgcn_mfma_f32_16x16x32_bf16(sfh[s0 + 3], bfrag, a3, 0, 0, 0);
                a0 = __builtin_amdgcn_mfma_f32_16x16x32_bf16(sfl[s0 + 0], bfrag, a0, 0, 0, 0);
                a1 = __builtin_amdgcn_mfma_f32_16x16x32_bf16(sfl[s0 + 1], bfrag, a1, 0, 0, 0);
                a2 = __builtin_amdgcn_mfma_f32_16x16x32_bf16(sfl[s0 + 2], bfrag, a2, 0, 0, 0);
                a3 = __builtin_amdgcn_mfma_f32_16x16x32_bf16(sfl[s0 + 3], bfrag, a3, 0, 0, 0);
                CONSUME(a0, s0 + 0);
                CONSUME(a1, s0 + 1);
                CONSUME(a2, s0 + 2);
                CONSUME(a3, s0 + 3);
            }
            #undef CONSUME
            #undef CHAIN

            // ---- merge the 4 disjoint g-lane sets: all lanes end with the SAME set ----
            unsigned m0 = umin_u(k0, __shfl_xor(k7, 32, 64));
            unsigned m1 = umin_u(k1, __shfl_xor(k6, 32, 64));
            unsigned m2 = umin_u(k2, __shfl_xor(k5, 32, 64));
            unsigned m3 = umin_u(k3, __shfl_xor(k4, 32, 64));
            unsigned m4 = umin_u(k4, __shfl_xor(k3, 32, 64));
            unsigned m5 = umin_u(k5, __shfl_xor(k2, 32, 64));
            unsigned m6 = umin_u(k6, __shfl_xor(k1, 32, 64));
            unsigned m7 = umin_u(k7, __shfl_xor(k0, 32, 64));
            #define CEX(a, bq) do { unsigned _lo = umin_u(a, bq); unsigned _hi = umax_u(a, bq); a = _lo; bq = _hi; } while (0)
            CEX(m0, m4); CEX(m1, m5); CEX(m2, m6); CEX(m3, m7);
            CEX(m0, m2); CEX(m1, m3); CEX(m4, m6); CEX(m5, m7);
            CEX(m0, m1); CEX(m2, m3); CEX(m4, m5); CEX(m6, m7);
            #undef CEX
            unsigned f0 = umin_u(m0, __shfl_xor(m7, 16, 64));
            unsigned f1 = umin_u(m1, __shfl_xor(m6, 16, 64));
            unsigned f2 = umin_u(m2, __shfl_xor(m5, 16, 64));
            unsigned f3 = umin_u(m3, __shfl_xor(m4, 16, 64));
            unsigned f4 = umin_u(m4, __shfl_xor(m3, 16, 64));
            unsigned f5 = umin_u(m5, __shfl_xor(m2, 16, 64));
            unsigned f6 = umin_u(m6, __shfl_xor(m1, 16, 64));
            unsigned f7 = umin_u(m7, __shfl_xor(m0, 16, 64));

            // ---- fused epilogue: lane g handles dims [4g, 4g+4) ----
            uint2 th = *(const uint2*)(tp + 2 * g);
            uint2 tl = *(const uint2*)(tp + 8 + 2 * g);
            float tfa = uasf(th.x << 16)         + uasf(tl.x << 16);
            float tfb = uasf(th.x & 0xFFFF0000u) + uasf(tl.x & 0xFFFF0000u);
            float tfc = uasf(th.y << 16)         + uasf(tl.y << 16);
            float tfd = uasf(th.y & 0xFFFF0000u) + uasf(tl.y & 0xFFFF0000u);
            f32x4 uc4 = *(const f32x4*)&ucS[g4];
            f32x4 wo4 = *(const f32x4*)&WoS[g4];
            float part = (g == 0) ? ucS[HH] : 0.0f;
            part = fmaf(tfa, uc4.x, part);
            part = fmaf(tfb, uc4.y, part);
            part = fmaf(tfc, uc4.z, part);
            part = fmaf(tfd, uc4.w, part);
            f32x4 mx = {-INFINITY, -INFINITY, -INFINITY, -INFINITY};
            mx = __builtin_elementwise_max(mx, *(const f32x4*)&proj[f0 & 127u][g4]);
            mx = __builtin_elementwise_max(mx, *(const f32x4*)&proj[f1 & 127u][g4]);
            mx = __builtin_elementwise_max(mx, *(const f32x4*)&proj[f2 & 127u][g4]);
            mx = __builtin_elementwise_max(mx, *(const f32x4*)&proj[f3 & 127u][g4]);
            mx = __builtin_elementwise_max(mx, *(const f32x4*)&proj[f4 & 127u][g4]);
            mx = __builtin_elementwise_max(mx, *(const f32x4*)&proj[f5 & 127u][g4]);
            mx = __builtin_elementwise_max(mx, *(const f32x4*)&proj[f6 & 127u][g4]);
            mx = __builtin_elementwise_max(mx, *(const f32x4*)&proj[f7 & 127u][g4]);
            part = fmaf(mx.x, wo4.x, part);
            part = fmaf(mx.y, wo4.y, part);
            part = fmaf(mx.z, wo4.z, part);
            part = fmaf(mx.w, wo4.w, part);
            part += __shfl_xor(part, 16, 64);
            part += __shfl_xor(part, 32, 64);
            float sg = __builtin_amdgcn_rcpf(1.0f + __builtin_amdgcn_exp2f(part * -1.44269504088896341f));
            if (g == 0) wsum += sg;
        }
    }

    // ---- block mean-pool (g!=0 lanes contribute zero) ----
    #pragma unroll
    for (int off = 32; off > 0; off >>= 1)
        wsum += __shfl_down(wsum, off, 64);
    if ((tid & 63) == 0) sred[tid >> 6] = wsum;
    __syncthreads();
    if (tid == 0) {
        float tot = 0.0f;
        #pragma unroll
        for (int w2 = 0; w2 < TPB / 64; ++w2) tot += sred[w2];
        out[b]      = tot * (1.0f / NTRK);
        out[BB + b] = (float)b;
    }
}

extern "C" void kernel_launch(void* const* d_in, const int* in_sizes, int n_in,
                              void* d_out, int out_size, void* d_ws, size_t ws_size,
                              hipStream_t stream) {
    const float* x_sv  = (const float*)d_in[0];
    const float* x_trk = (const float*)d_in[1];
    const float* W1s = (const float*)d_in[4];
    const float* b1s = (const float*)d_in[5];
    const float* W2s = (const float*)d_in[6];
    const float* b2s = (const float*)d_in[7];
    const float* W1t = (const float*)d_in[8];
    const float* b1t = (const float*)d_in[9];
    const float* W2t = (const float*)d_in[10];
    const float* b2t = (const float*)d_in[11];
    const float* We  = (const float*)d_in[12];
    const float* be  = (const float*)d_in[13];
    const float* Wo  = (const float*)d_in[14];
    const float* bo  = (const float*)d_in[15];
    float* out = (float*)d_out;

    fused_all<<<BB, TPB, 0, stream>>>(x_sv, x_trk,
                                      W1s, b1s, W2s, b2s,
                                      W1t, b1t, W2t, b2t,
                                      We, be, Wo, bo,
                                      out);
}

// Round 8
// 123.565 us; speedup vs baseline: 1.1178x; 1.1178x over previous
//
#include <hip/hip_runtime.h>
#include <cmath>

#define BB   512
#define NSV  128
#define NTRK 512
#define KK   8
#define HH   16
#define TPB  512
#define TST  36            // T row stride in shorts (72B): [thi 16][tlo 16][htsq f32]  18 dwords, gcd(18,32)=2
#define SST  36            // S row stride in shorts: [shi 16][slo 16][pad]
#define PSTR 20            // proj stride (f32)

typedef float    f32x4  __attribute__((ext_vector_type(4)));
typedef short    bf16x8 __attribute__((ext_vector_type(8)));
typedef unsigned u32x4  __attribute__((ext_vector_type(4)));

__device__ __forceinline__ float elu_f(float x) {
    float e = __builtin_amdgcn_exp2f(x * 1.44269504088896341f) - 1.0f;
    return x > 0.0f ? x : e;
}
__device__ __forceinline__ unsigned umin_u(unsigned a, unsigned b) { return a < b ? a : b; }
__device__ __forceinline__ unsigned umax_u(unsigned a, unsigned b) { return a > b ? a : b; }
__device__ __forceinline__ unsigned med3u(unsigned a, unsigned b, unsigned c) {
    unsigned d;
    asm("v_med3_u32 %0, %1, %2, %3" : "=v"(d) : "v"(a), "v"(b), "v"(c));
    return d;
}
__device__ __forceinline__ bf16x8 mk_bf8(uint2 a, uint2 b) {
    u32x4 u; u.x = a.x; u.y = a.y; u.z = b.x; u.w = b.y;
    return __builtin_bit_cast(bf16x8, u);
}
__device__ __forceinline__ float uasf(unsigned u) { return __uint_as_float(u); }

// One block = one batch. 512 threads, 8 waves.
// Phase A: per-thread track MLP -> split-bf16 [thi|tlo]+htsq rows (stride 36
//          shorts -> gcd-2 banks, free); threads 0-127: SV MLP -> S rows (same
//          stride) + hsq + proj.
// Phase B: ss-OUTER / track-tile-INNER loop. Per wave: hoist only the 4 track
//          B-frags (16 VGPR) + htsq. Per ss: load A-frags (hi/lo) ONCE, 8 MFMA
//          (2 per tile, split-bf16 exact dot), consume into 4 per-tile med3
//          top-8 chains (32 persistent regs). After the ss loop: per tile,
//          2-stage shfl_xor bitonic merge (all 4 g-lanes end with the SAME
//          top-8 set) + fused epilogue (lane g does dims 4g..4g+3 of
//          mx.Wo + tf.u, 2 shfl_xor adds, sigmoid).
// [R7 note: identical kernel resubmitted — the R7 bench died on container
//  acquisition (no data).]
// [R6 errata: hoisting all 16 SV frags (64 persistent VGPR) spilled under
//  (512,4): WRITE_SIZE 32B->62MB, 123us. Loop interchange gets the same
//  4x A-frag read reduction with ~90 VGPR peak.]
// [R5 errata: gcd-4 row strides -> 2.34M bank-conflict cy; A-frags re-read 4x;
//  serialized phase C.]
__global__ __launch_bounds__(TPB, 4) void fused_all(
    const float* __restrict__ x_sv, const float* __restrict__ x_trk,
    const float* __restrict__ W1s, const float* __restrict__ b1s,
    const float* __restrict__ W2s, const float* __restrict__ b2s,
    const float* __restrict__ W1t, const float* __restrict__ b1t,
    const float* __restrict__ W2t, const float* __restrict__ b2t,
    const float* __restrict__ We,  const float* __restrict__ be,
    const float* __restrict__ Wo,  const float* __restrict__ bo,
    float* __restrict__ out)
{
    __shared__ __align__(16) short Tsh[NTRK * TST];   // 36.9 KB
    __shared__ __align__(16) short Ssh[NSV * SST];    // 9.2 KB
    __shared__ __align__(16) float hsqS[NSV];         // 0.5 KB
    __shared__ __align__(16) float proj[NSV][PSTR];   // 10.2 KB
    __shared__ __align__(16) float ucS[HH + 1];
    __shared__ __align__(16) float WoS[HH];
    __shared__ float sred[TPB / 64];

    const int b = blockIdx.x, tid = threadIdx.x;

    // ================= phase A =================
    {
        const float* xp = x_trk + (size_t)(b * NTRK + tid) * 8;
        float x[8];
        *(float4*)&x[0] = *(const float4*)&xp[0];
        *(float4*)&x[4] = *(const float4*)&xp[4];
        float hb[HH];
        #pragma unroll
        for (int h = 0; h < HH; ++h) {
            float a = b1t[h];
            #pragma unroll
            for (int i = 0; i < 8; ++i) a += x[i] * W1t[i * HH + h];
            hb[h] = elu_f(a);
        }
        float tf[HH], sq = 0.0f;
        #pragma unroll
        for (int h2 = 0; h2 < HH; ++h2) {
            float a = b2t[h2];
            #pragma unroll
            for (int h = 0; h < HH; ++h) a += hb[h] * W2t[h * HH + h2];
            tf[h2] = a;
            sq += a * a;
        }
        unsigned hw[8], lw[8];
        #pragma unroll
        for (int j = 0; j < 8; ++j) {
            float f0 = tf[2 * j], f1 = tf[2 * j + 1];
            unsigned u0 = __float_as_uint(f0) & 0xFFFF0000u;
            unsigned u1 = __float_as_uint(f1) & 0xFFFF0000u;
            hw[j] = (u0 >> 16) | u1;
            float r0 = f0 - uasf(u0);
            float r1 = f1 - uasf(u1);
            lw[j] = (__float_as_uint(r0) >> 16) | (__float_as_uint(r1) & 0xFFFF0000u);
        }
        unsigned* tr = (unsigned*)&Tsh[tid * TST];
        *(uint2*)(tr + 0)  = make_uint2(hw[0], hw[1]);
        *(uint2*)(tr + 2)  = make_uint2(hw[2], hw[3]);
        *(uint2*)(tr + 4)  = make_uint2(hw[4], hw[5]);
        *(uint2*)(tr + 6)  = make_uint2(hw[6], hw[7]);
        *(uint2*)(tr + 8)  = make_uint2(lw[0], lw[1]);
        *(uint2*)(tr + 10) = make_uint2(lw[2], lw[3]);
        *(uint2*)(tr + 12) = make_uint2(lw[4], lw[5]);
        *(uint2*)(tr + 14) = make_uint2(lw[6], lw[7]);
        ((float*)tr)[16] = 0.5f * sq;
    }

    if (tid < NSV) {
        const float* xp = x_sv + (size_t)(b * NSV + tid) * 2;
        float x0 = xp[0], x1 = xp[1];
        float hb[HH];
        #pragma unroll
        for (int h = 0; h < HH; ++h)
            hb[h] = elu_f(x0 * W1s[h] + x1 * W1s[HH + h] + b1s[h]);
        float o[HH], sq = 0.0f;
        #pragma unroll
        for (int h2 = 0; h2 < HH; ++h2) {
            float a = b2s[h2];
            #pragma unroll
            for (int h = 0; h < HH; ++h) a += hb[h] * W2s[h * HH + h2];
            o[h2] = a;
            sq += a * a;
        }
        unsigned hw[8], lw[8];
        #pragma unroll
        for (int j = 0; j < 8; ++j) {
            float f0 = o[2 * j], f1 = o[2 * j + 1];
            unsigned u0 = __float_as_uint(f0) & 0xFFFF0000u;
            unsigned u1 = __float_as_uint(f1) & 0xFFFF0000u;
            hw[j] = (u0 >> 16) | u1;
            float r0 = f0 - uasf(u0);
            float r1 = f1 - uasf(u1);
            lw[j] = (__float_as_uint(r0) >> 16) | (__float_as_uint(r1) & 0xFFFF0000u);
        }
        unsigned* sr = (unsigned*)&Ssh[tid * SST];
        *(uint2*)(sr + 0)  = make_uint2(hw[0], hw[1]);
        *(uint2*)(sr + 2)  = make_uint2(hw[2], hw[3]);
        *(uint2*)(sr + 4)  = make_uint2(hw[4], hw[5]);
        *(uint2*)(sr + 6)  = make_uint2(hw[6], hw[7]);
        *(uint2*)(sr + 8)  = make_uint2(lw[0], lw[1]);
        *(uint2*)(sr + 10) = make_uint2(lw[2], lw[3]);
        *(uint2*)(sr + 12) = make_uint2(lw[4], lw[5]);
        *(uint2*)(sr + 14) = make_uint2(lw[6], lw[7]);
        hsqS[tid] = 0.5f * sq;
        #pragma unroll
        for (int h = 0; h < HH; ++h) {
            float a = 0.0f;
            #pragma unroll
            for (int j = 0; j < HH; ++j) a += o[j] * We[(HH + j) * HH + h];
            proj[tid][h] = a;
        }
    } else if (tid < NSV + HH) {
        int j = tid - NSV;
        float a = 0.0f;
        #pragma unroll
        for (int h = 0; h < HH; ++h)
            a += (We[j * HH + h] - We[(HH + j) * HH + h]) * Wo[h];
        ucS[j] = a;
    } else if (tid < NSV + 2 * HH) {
        int j = tid - NSV - HH;
        WoS[j] = Wo[j];
    } else if (tid == NSV + 2 * HH) {
        float a = bo[0];
        #pragma unroll
        for (int h = 0; h < HH; ++h) a += be[h] * Wo[h];
        ucS[HH] = a;
    }

    __syncthreads();

    // ================= phase B: MFMA + top-8 + fused epilogue =================
    float wsum = 0.0f;
    {
        const int lane = tid & 63;
        const int w    = tid >> 6;
        const int c    = lane & 15;
        const int g    = lane >> 4;
        const int g4   = g << 2;
        const int gd   = (g & 1) << 2;   // A-frag dword offset (dup-K)

        // hoist the 4 track B-frags + htsq (16+4 VGPR persistent)
        const unsigned* tp0 = (const unsigned*)&Tsh[((w     ) * 16 + c) * TST];
        const unsigned* tp1 = (const unsigned*)&Tsh[((w +  8) * 16 + c) * TST];
        const unsigned* tp2 = (const unsigned*)&Tsh[((w + 16) * 16 + c) * TST];
        const unsigned* tp3 = (const unsigned*)&Tsh[((w + 24) * 16 + c) * TST];
        bf16x8 bf0 = mk_bf8(*(const uint2*)(tp0 + g * 4), *(const uint2*)(tp0 + g * 4 + 2));
        bf16x8 bf1 = mk_bf8(*(const uint2*)(tp1 + g * 4), *(const uint2*)(tp1 + g * 4 + 2));
        bf16x8 bf2 = mk_bf8(*(const uint2*)(tp2 + g * 4), *(const uint2*)(tp2 + g * 4 + 2));
        bf16x8 bf3 = mk_bf8(*(const uint2*)(tp3 + g * 4), *(const uint2*)(tp3 + g * 4 + 2));
        const float ht0 = ((const float*)tp0)[16];
        const float ht1 = ((const float*)tp1)[16];
        const float ht2 = ((const float*)tp2)[16];
        const float ht3 = ((const float*)tp3)[16];

        // per-tile selection state: 32 named regs
        unsigned k00=~0u,k01=~0u,k02=~0u,k03=~0u,k04=~0u,k05=~0u,k06=~0u,k07=~0u;
        unsigned k10=~0u,k11=~0u,k12=~0u,k13=~0u,k14=~0u,k15=~0u,k16=~0u,k17=~0u;
        unsigned k20=~0u,k21=~0u,k22=~0u,k23=~0u,k24=~0u,k25=~0u,k26=~0u,k27=~0u;
        unsigned k30=~0u,k31=~0u,k32=~0u,k33=~0u,k34=~0u,k35=~0u,k36=~0u,k37=~0u;

        #define CHAIN(v,K0,K1,K2,K3,K4,K5,K6,K7)                           \
            do {                                                           \
                unsigned nk0 = umin_u(v, K0);                              \
                unsigned nk1 = med3u(v, K0, K1);                           \
                unsigned nk2 = med3u(v, K1, K2);                           \
                unsigned nk3 = med3u(v, K2, K3);                           \
                unsigned nk4 = med3u(v, K3, K4);                           \
                unsigned nk5 = med3u(v, K4, K5);                           \
                unsigned nk6 = med3u(v, K5, K6);                           \
                unsigned nk7 = med3u(v, K6, K7);                           \
                K0 = nk0; K1 = nk1; K2 = nk2; K3 = nk3;                    \
                K4 = nk4; K5 = nk5; K6 = nk6; K7 = nk7;                    \
            } while (0)

        #define CONSUME(T, accv)                                           \
            do {                                                           \
                float e0 = fmaxf((ht##T - accv.x) + hq.x, 0.0f);           \
                float e1 = fmaxf((ht##T - accv.y) + hq.y, 0.0f);           \
                float e2 = fmaxf((ht##T - accv.z) + hq.z, 0.0f);           \
                float e3 = fmaxf((ht##T - accv.w) + hq.w, 0.0f);           \
                unsigned v0 = (__float_as_uint(e0) & 0xFFFFFF80u) | (unsigned)(sbase + 0); \
                CHAIN(v0,k##T##0,k##T##1,k##T##2,k##T##3,k##T##4,k##T##5,k##T##6,k##T##7); \
                unsigned v1 = (__float_as_uint(e1) & 0xFFFFFF80u) | (unsigned)(sbase + 1); \
                CHAIN(v1,k##T##0,k##T##1,k##T##2,k##T##3,k##T##4,k##T##5,k##T##6,k##T##7); \
                unsigned v2 = (__float_as_uint(e2) & 0xFFFFFF80u) | (unsigned)(sbase + 2); \
                CHAIN(v2,k##T##0,k##T##1,k##T##2,k##T##3,k##T##4,k##T##5,k##T##6,k##T##7); \
                unsigned v3 = (__float_as_uint(e3) & 0xFFFFFF80u) | (unsigned)(sbase + 3); \
                CHAIN(v3,k##T##0,k##T##1,k##T##2,k##T##3,k##T##4,k##T##5,k##T##6,k##T##7); \
            } while (0)

        #pragma unroll
        for (int ss = 0; ss < 8; ++ss) {
            const unsigned* sp = (const unsigned*)&Ssh[(ss * 16 + c) * SST];
            bf16x8 ah = mk_bf8(*(const uint2*)(sp + gd), *(const uint2*)(sp + gd + 2));
            bf16x8 al = mk_bf8(*(const uint2*)(sp + 8 + gd), *(const uint2*)(sp + 8 + gd + 2));
            f32x4 hq = *(const f32x4*)&hsqS[ss * 16 + g4];
            const int sbase = ss * 16 + g4;
            f32x4 a0 = {0.f, 0.f, 0.f, 0.f}, a1 = a0, a2 = a0, a3 = a0;
            a0 = __builtin_amdgcn_mfma_f32_16x16x32_bf16(ah, bf0, a0, 0, 0, 0);
            a1 = __builtin_amdgcn_mfma_f32_16x16x32_bf16(ah, bf1, a1, 0, 0, 0);
            a2 = __builtin_amdgcn_mfma_f32_16x16x32_bf16(ah, bf2, a2, 0, 0, 0);
            a3 = __builtin_amdgcn_mfma_f32_16x16x32_bf16(ah, bf3, a3, 0, 0, 0);
            a0 = __builtin_amdgcn_mfma_f32_16x16x32_bf16(al, bf0, a0, 0, 0, 0);
            a1 = __builtin_amdgcn_mfma_f32_16x16x32_bf16(al, bf1, a1, 0, 0, 0);
            a2 = __builtin_amdgcn_mfma_f32_16x16x32_bf16(al, bf2, a2, 0, 0, 0);
            a3 = __builtin_amdgcn_mfma_f32_16x16x32_bf16(al, bf3, a3, 0, 0, 0);
            CONSUME(0, a0);
            CONSUME(1, a1);
            CONSUME(2, a2);
            CONSUME(3, a3);
        }
        #undef CONSUME
        #undef CHAIN

        // ---- per tile: merge 4 disjoint g-lane sets + fused epilogue ----
        #define CEX(a, bq) do { unsigned _lo = umin_u(a, bq); unsigned _hi = umax_u(a, bq); a = _lo; bq = _hi; } while (0)
        #define MERGE_EPI(T, TP)                                           \
            do {                                                           \
                unsigned m0 = umin_u(k##T##0, __shfl_xor(k##T##7, 32, 64));\
                unsigned m1 = umin_u(k##T##1, __shfl_xor(k##T##6, 32, 64));\
                unsigned m2 = umin_u(k##T##2, __shfl_xor(k##T##5, 32, 64));\
                unsigned m3 = umin_u(k##T##3, __shfl_xor(k##T##4, 32, 64));\
                unsigned m4 = umin_u(k##T##4, __shfl_xor(k##T##3, 32, 64));\
                unsigned m5 = umin_u(k##T##5, __shfl_xor(k##T##2, 32, 64));\
                unsigned m6 = umin_u(k##T##6, __shfl_xor(k##T##1, 32, 64));\
                unsigned m7 = umin_u(k##T##7, __shfl_xor(k##T##0, 32, 64));\
                CEX(m0, m4); CEX(m1, m5); CEX(m2, m6); CEX(m3, m7);        \
                CEX(m0, m2); CEX(m1, m3); CEX(m4, m6); CEX(m5, m7);        \
                CEX(m0, m1); CEX(m2, m3); CEX(m4, m5); CEX(m6, m7);        \
                unsigned f0 = umin_u(m0, __shfl_xor(m7, 16, 64));          \
                unsigned f1 = umin_u(m1, __shfl_xor(m6, 16, 64));          \
                unsigned f2 = umin_u(m2, __shfl_xor(m5, 16, 64));          \
                unsigned f3 = umin_u(m3, __shfl_xor(m4, 16, 64));          \
                unsigned f4 = umin_u(m4, __shfl_xor(m3, 16, 64));          \
                unsigned f5 = umin_u(m5, __shfl_xor(m2, 16, 64));          \
                unsigned f6 = umin_u(m6, __shfl_xor(m1, 16, 64));          \
                unsigned f7 = umin_u(m7, __shfl_xor(m0, 16, 64));          \
                uint2 th = *(const uint2*)((TP) + 2 * g);                  \
                uint2 tl = *(const uint2*)((TP) + 8 + 2 * g);              \
                float tfa = uasf(th.x << 16)         + uasf(tl.x << 16);   \
                float tfb = uasf(th.x & 0xFFFF0000u) + uasf(tl.x & 0xFFFF0000u); \
                float tfc = uasf(th.y << 16)         + uasf(tl.y << 16);   \
                float tfd = uasf(th.y & 0xFFFF0000u) + uasf(tl.y & 0xFFFF0000u); \
                f32x4 uc4 = *(const f32x4*)&ucS[g4];                       \
                f32x4 wo4 = *(const f32x4*)&WoS[g4];                       \
                float part = (g == 0) ? ucS[HH] : 0.0f;                    \
                part = fmaf(tfa, uc4.x, part);                             \
                part = fmaf(tfb, uc4.y, part);                             \
                part = fmaf(tfc, uc4.z, part);                             \
                part = fmaf(tfd, uc4.w, part);                             \
                f32x4 mx = {-INFINITY, -INFINITY, -INFINITY, -INFINITY};   \
                mx = __builtin_elementwise_max(mx, *(const f32x4*)&proj[f0 & 127u][g4]); \
                mx = __builtin_elementwise_max(mx, *(const f32x4*)&proj[f1 & 127u][g4]); \
                mx = __builtin_elementwise_max(mx, *(const f32x4*)&proj[f2 & 127u][g4]); \
                mx = __builtin_elementwise_max(mx, *(const f32x4*)&proj[f3 & 127u][g4]); \
                mx = __builtin_elementwise_max(mx, *(const f32x4*)&proj[f4 & 127u][g4]); \
                mx = __builtin_elementwise_max(mx, *(const f32x4*)&proj[f5 & 127u][g4]); \
                mx = __builtin_elementwise_max(mx, *(const f32x4*)&proj[f6 & 127u][g4]); \
                mx = __builtin_elementwise_max(mx, *(const f32x4*)&proj[f7 & 127u][g4]); \
                part = fmaf(mx.x, wo4.x, part);                            \
                part = fmaf(mx.y, wo4.y, part);                            \
                part = fmaf(mx.z, wo4.z, part);                            \
                part = fmaf(mx.w, wo4.w, part);                            \
                part += __shfl_xor(part, 16, 64);                          \
                part += __shfl_xor(part, 32, 64);                          \
                float sg = __builtin_amdgcn_rcpf(1.0f + __builtin_amdgcn_exp2f(part * -1.44269504088896341f)); \
                if (g == 0) wsum += sg;                                    \
            } while (0)

        MERGE_EPI(0, tp0);
        MERGE_EPI(1, tp1);
        MERGE_EPI(2, tp2);
        MERGE_EPI(3, tp3);
        #undef MERGE_EPI
        #undef CEX
    }

    // ---- block mean-pool (g!=0 lanes contribute zero) ----
    #pragma unroll
    for (int off = 32; off > 0; off >>= 1)
        wsum += __shfl_down(wsum, off, 64);
    if ((tid & 63) == 0) sred[tid >> 6] = wsum;
    __syncthreads();
    if (tid == 0) {
        float tot = 0.0f;
        #pragma unroll
        for (int w2 = 0; w2 < TPB / 64; ++w2) tot += sred[w2];
        out[b]      = tot * (1.0f / NTRK);
        out[BB + b] = (float)b;
    }
}

extern "C" void kernel_launch(void* const* d_in, const int* in_sizes, int n_in,
                              void* d_out, int out_size, void* d_ws, size_t ws_size,
                              hipStream_t stream) {
    const float* x_sv  = (const float*)d_in[0];
    const float* x_trk = (const float*)d_in[1];
    const float* W1s = (const float*)d_in[4];
    const float* b1s = (const float*)d_in[5];
    const float* W2s = (const float*)d_in[6];
    const float* b2s = (const float*)d_in[7];
    const float* W1t = (const float*)d_in[8];
    const float* b1t = (const float*)d_in[9];
    const float* W2t = (const float*)d_in[10];
    const float* b2t = (const float*)d_in[11];
    const float* We  = (const float*)d_in[12];
    const float* be  = (const float*)d_in[13];
    const float* Wo  = (const float*)d_in[14];
    const float* bo  = (const float*)d_in[15];
    float* out = (float*)d_out;

    fused_all<<<BB, TPB, 0, stream>>>(x_sv, x_trk,
                                      W1s, b1s, W2s, b2s,
                                      W1t, b1t, W2t, b2t,
                                      We, be, Wo, bo,
                                      out);
}

// Round 9
// 115.207 us; speedup vs baseline: 1.1989x; 1.0725x over previous
//
#include <hip/hip_runtime.h>
#include <cmath>

#define BB   512
#define NSV  128
#define NTRK 512
#define KK   8
#define HH   16
#define TPB  1024          // 16 waves; threads 0-511 track MLP, 512-639 SV MLP (parallel)
#define TST  36            // T row stride in shorts (72B): [thi 16][tlo 16][htsq f32]  18 dwords, gcd(18,32)=2
#define SST  36            // S row stride in shorts: [shi 16][slo 16][pad]
#define PSTR 20            // proj stride (f32)

typedef float    f32x4  __attribute__((ext_vector_type(4)));
typedef short    bf16x8 __attribute__((ext_vector_type(8)));
typedef unsigned u32x4  __attribute__((ext_vector_type(4)));

__device__ __forceinline__ float elu_f(float x) {
    float e = __builtin_amdgcn_exp2f(x * 1.44269504088896341f) - 1.0f;
    return x > 0.0f ? x : e;
}
__device__ __forceinline__ unsigned umin_u(unsigned a, unsigned b) { return a < b ? a : b; }
__device__ __forceinline__ unsigned umax_u(unsigned a, unsigned b) { return a > b ? a : b; }
__device__ __forceinline__ unsigned med3u(unsigned a, unsigned b, unsigned c) {
    unsigned d;
    asm("v_med3_u32 %0, %1, %2, %3" : "=v"(d) : "v"(a), "v"(b), "v"(c));
    return d;
}
__device__ __forceinline__ bf16x8 mk_bf8(uint2 a, uint2 b) {
    u32x4 u; u.x = a.x; u.y = a.y; u.z = b.x; u.w = b.y;
    return __builtin_bit_cast(bf16x8, u);
}
__device__ __forceinline__ float uasf(unsigned u) { return __uint_as_float(u); }

// One block = one batch. 1024 threads, 16 waves (8 waves/SIMD at 2 blocks/CU).
// R9: R8 re-tiled for 2x TLP. R8 was 512 threads -> grid-pinned 16 waves/CU
// (4/SIMD) and 34% occupancy: the ds_read->MFMA->chain dependency latency was
// exposed (essential issue work ~12us vs 41.8us measured). 16 waves/block,
// each wave owns 2 track-tiles (was 4): per-wave work halves, per-CU work
// unchanged, waves/SIMD 4->8. SV MLP now parallel with track MLP (threads
// 512-639 vs 0-511) instead of serialized on threads 0-127.
// launch_bounds(1024,8) caps VGPR at 64 (R8 used 56 with MORE persistent
// state; spill tattletale = WRITE_SIZE).
// [R6 errata: 64 persistent frag VGPRs spilled -> 62MB scratch. R5: gcd-4
//  LDS strides -> 2.3M conflict cy. R4: ds_read broadcast rows = 61us wall.
//  R1: SMEM ooo drains. R2/R3: private-array scratch.]
__global__ __launch_bounds__(TPB, 8) void fused_all(
    const float* __restrict__ x_sv, const float* __restrict__ x_trk,
    const float* __restrict__ W1s, const float* __restrict__ b1s,
    const float* __restrict__ W2s, const float* __restrict__ b2s,
    const float* __restrict__ W1t, const float* __restrict__ b1t,
    const float* __restrict__ W2t, const float* __restrict__ b2t,
    const float* __restrict__ We,  const float* __restrict__ be,
    const float* __restrict__ Wo,  const float* __restrict__ bo,
    float* __restrict__ out)
{
    __shared__ __align__(16) short Tsh[NTRK * TST];   // 36.9 KB
    __shared__ __align__(16) short Ssh[NSV * SST];    // 9.2 KB
    __shared__ __align__(16) float hsqS[NSV];         // 0.5 KB
    __shared__ __align__(16) float proj[NSV][PSTR];   // 10.2 KB
    __shared__ __align__(16) float ucS[HH + 1];
    __shared__ __align__(16) float WoS[HH];
    __shared__ float sred[TPB / 64];

    const int b = blockIdx.x, tid = threadIdx.x;

    // ================= phase A (parallel thread ranges) =================
    if (tid < NTRK) {
        // track MLP for track tid
        const float* xp = x_trk + (size_t)(b * NTRK + tid) * 8;
        float x[8];
        *(float4*)&x[0] = *(const float4*)&xp[0];
        *(float4*)&x[4] = *(const float4*)&xp[4];
        float hb[HH];
        #pragma unroll
        for (int h = 0; h < HH; ++h) {
            float a = b1t[h];
            #pragma unroll
            for (int i = 0; i < 8; ++i) a += x[i] * W1t[i * HH + h];
            hb[h] = elu_f(a);
        }
        float tf[HH], sq = 0.0f;
        #pragma unroll
        for (int h2 = 0; h2 < HH; ++h2) {
            float a = b2t[h2];
            #pragma unroll
            for (int h = 0; h < HH; ++h) a += hb[h] * W2t[h * HH + h2];
            tf[h2] = a;
            sq += a * a;
        }
        unsigned hw[8], lw[8];
        #pragma unroll
        for (int j = 0; j < 8; ++j) {
            float f0 = tf[2 * j], f1 = tf[2 * j + 1];
            unsigned u0 = __float_as_uint(f0) & 0xFFFF0000u;
            unsigned u1 = __float_as_uint(f1) & 0xFFFF0000u;
            hw[j] = (u0 >> 16) | u1;
            float r0 = f0 - uasf(u0);
            float r1 = f1 - uasf(u1);
            lw[j] = (__float_as_uint(r0) >> 16) | (__float_as_uint(r1) & 0xFFFF0000u);
        }
        unsigned* tr = (unsigned*)&Tsh[tid * TST];
        *(uint2*)(tr + 0)  = make_uint2(hw[0], hw[1]);
        *(uint2*)(tr + 2)  = make_uint2(hw[2], hw[3]);
        *(uint2*)(tr + 4)  = make_uint2(hw[4], hw[5]);
        *(uint2*)(tr + 6)  = make_uint2(hw[6], hw[7]);
        *(uint2*)(tr + 8)  = make_uint2(lw[0], lw[1]);
        *(uint2*)(tr + 10) = make_uint2(lw[2], lw[3]);
        *(uint2*)(tr + 12) = make_uint2(lw[4], lw[5]);
        *(uint2*)(tr + 14) = make_uint2(lw[6], lw[7]);
        ((float*)tr)[16] = 0.5f * sq;
    } else if (tid < NTRK + NSV) {
        const int s = tid - NTRK;
        const float* xp = x_sv + (size_t)(b * NSV + s) * 2;
        float x0 = xp[0], x1 = xp[1];
        float hb[HH];
        #pragma unroll
        for (int h = 0; h < HH; ++h)
            hb[h] = elu_f(x0 * W1s[h] + x1 * W1s[HH + h] + b1s[h]);
        float o[HH], sq = 0.0f;
        #pragma unroll
        for (int h2 = 0; h2 < HH; ++h2) {
            float a = b2s[h2];
            #pragma unroll
            for (int h = 0; h < HH; ++h) a += hb[h] * W2s[h * HH + h2];
            o[h2] = a;
            sq += a * a;
        }
        unsigned hw[8], lw[8];
        #pragma unroll
        for (int j = 0; j < 8; ++j) {
            float f0 = o[2 * j], f1 = o[2 * j + 1];
            unsigned u0 = __float_as_uint(f0) & 0xFFFF0000u;
            unsigned u1 = __float_as_uint(f1) & 0xFFFF0000u;
            hw[j] = (u0 >> 16) | u1;
            float r0 = f0 - uasf(u0);
            float r1 = f1 - uasf(u1);
            lw[j] = (__float_as_uint(r0) >> 16) | (__float_as_uint(r1) & 0xFFFF0000u);
        }
        unsigned* sr = (unsigned*)&Ssh[s * SST];
        *(uint2*)(sr + 0)  = make_uint2(hw[0], hw[1]);
        *(uint2*)(sr + 2)  = make_uint2(hw[2], hw[3]);
        *(uint2*)(sr + 4)  = make_uint2(hw[4], hw[5]);
        *(uint2*)(sr + 6)  = make_uint2(hw[6], hw[7]);
        *(uint2*)(sr + 8)  = make_uint2(lw[0], lw[1]);
        *(uint2*)(sr + 10) = make_uint2(lw[2], lw[3]);
        *(uint2*)(sr + 12) = make_uint2(lw[4], lw[5]);
        *(uint2*)(sr + 14) = make_uint2(lw[6], lw[7]);
        hsqS[s] = 0.5f * sq;
        #pragma unroll
        for (int h = 0; h < HH; ++h) {
            float a = 0.0f;
            #pragma unroll
            for (int j = 0; j < HH; ++j) a += o[j] * We[(HH + j) * HH + h];
            proj[s][h] = a;
        }
    } else if (tid < NTRK + NSV + HH) {
        int j = tid - NTRK - NSV;
        float a = 0.0f;
        #pragma unroll
        for (int h = 0; h < HH; ++h)
            a += (We[j * HH + h] - We[(HH + j) * HH + h]) * Wo[h];
        ucS[j] = a;
    } else if (tid < NTRK + NSV + 2 * HH) {
        int j = tid - NTRK - NSV - HH;
        WoS[j] = Wo[j];
    } else if (tid == NTRK + NSV + 2 * HH) {
        float a = bo[0];
        #pragma unroll
        for (int h = 0; h < HH; ++h) a += be[h] * Wo[h];
        ucS[HH] = a;
    }

    __syncthreads();

    // ================= phase B: MFMA + top-8 + fused epilogue =================
    float wsum = 0.0f;
    {
        const int lane = tid & 63;
        const int w    = tid >> 6;        // wave 0..15
        const int c    = lane & 15;
        const int g    = lane >> 4;
        const int g4   = g << 2;
        const int gd   = (g & 1) << 2;    // A-frag dword offset (dup-K)

        // hoist the 2 track B-frags + htsq (8+2 VGPR persistent)
        const unsigned* tp0 = (const unsigned*)&Tsh[((w     ) * 16 + c) * TST];
        const unsigned* tp1 = (const unsigned*)&Tsh[((w + 16) * 16 + c) * TST];
        bf16x8 bf0 = mk_bf8(*(const uint2*)(tp0 + g * 4), *(const uint2*)(tp0 + g * 4 + 2));
        bf16x8 bf1 = mk_bf8(*(const uint2*)(tp1 + g * 4), *(const uint2*)(tp1 + g * 4 + 2));
        const float ht0 = ((const float*)tp0)[16];
        const float ht1 = ((const float*)tp1)[16];

        // per-tile selection state: 16 named regs
        unsigned k00=~0u,k01=~0u,k02=~0u,k03=~0u,k04=~0u,k05=~0u,k06=~0u,k07=~0u;
        unsigned k10=~0u,k11=~0u,k12=~0u,k13=~0u,k14=~0u,k15=~0u,k16=~0u,k17=~0u;

        #define CHAIN(v,K0,K1,K2,K3,K4,K5,K6,K7)                           \
            do {                                                           \
                unsigned nk0 = umin_u(v, K0);                              \
                unsigned nk1 = med3u(v, K0, K1);                           \
                unsigned nk2 = med3u(v, K1, K2);                           \
                unsigned nk3 = med3u(v, K2, K3);                           \
                unsigned nk4 = med3u(v, K3, K4);                           \
                unsigned nk5 = med3u(v, K4, K5);                           \
                unsigned nk6 = med3u(v, K5, K6);                           \
                unsigned nk7 = med3u(v, K6, K7);                           \
                K0 = nk0; K1 = nk1; K2 = nk2; K3 = nk3;                    \
                K4 = nk4; K5 = nk5; K6 = nk6; K7 = nk7;                    \
            } while (0)

        #define CONSUME(T, accv)                                           \
            do {                                                           \
                float e0 = fmaxf((ht##T - accv.x) + hq.x, 0.0f);           \
                float e1 = fmaxf((ht##T - accv.y) + hq.y, 0.0f);           \
                float e2 = fmaxf((ht##T - accv.z) + hq.z, 0.0f);           \
                float e3 = fmaxf((ht##T - accv.w) + hq.w, 0.0f);           \
                unsigned v0 = (__float_as_uint(e0) & 0xFFFFFF80u) | (unsigned)(sbase + 0); \
                CHAIN(v0,k##T##0,k##T##1,k##T##2,k##T##3,k##T##4,k##T##5,k##T##6,k##T##7); \
                unsigned v1 = (__float_as_uint(e1) & 0xFFFFFF80u) | (unsigned)(sbase + 1); \
                CHAIN(v1,k##T##0,k##T##1,k##T##2,k##T##3,k##T##4,k##T##5,k##T##6,k##T##7); \
                unsigned v2 = (__float_as_uint(e2) & 0xFFFFFF80u) | (unsigned)(sbase + 2); \
                CHAIN(v2,k##T##0,k##T##1,k##T##2,k##T##3,k##T##4,k##T##5,k##T##6,k##T##7); \
                unsigned v3 = (__float_as_uint(e3) & 0xFFFFFF80u) | (unsigned)(sbase + 3); \
                CHAIN(v3,k##T##0,k##T##1,k##T##2,k##T##3,k##T##4,k##T##5,k##T##6,k##T##7); \
            } while (0)

        #pragma unroll
        for (int ss = 0; ss < 8; ++ss) {
            const unsigned* sp = (const unsigned*)&Ssh[(ss * 16 + c) * SST];
            bf16x8 ah = mk_bf8(*(const uint2*)(sp + gd), *(const uint2*)(sp + gd + 2));
            bf16x8 al = mk_bf8(*(const uint2*)(sp + 8 + gd), *(const uint2*)(sp + 8 + gd + 2));
            f32x4 hq = *(const f32x4*)&hsqS[ss * 16 + g4];
            const int sbase = ss * 16 + g4;
            f32x4 a0 = {0.f, 0.f, 0.f, 0.f}, a1 = a0;
            a0 = __builtin_amdgcn_mfma_f32_16x16x32_bf16(ah, bf0, a0, 0, 0, 0);
            a1 = __builtin_amdgcn_mfma_f32_16x16x32_bf16(ah, bf1, a1, 0, 0, 0);
            a0 = __builtin_amdgcn_mfma_f32_16x16x32_bf16(al, bf0, a0, 0, 0, 0);
            a1 = __builtin_amdgcn_mfma_f32_16x16x32_bf16(al, bf1, a1, 0, 0, 0);
            CONSUME(0, a0);
            CONSUME(1, a1);
        }
        #undef CONSUME
        #undef CHAIN

        // ---- per tile: merge 4 disjoint g-lane sets + fused epilogue ----
        #define CEX(a, bq) do { unsigned _lo = umin_u(a, bq); unsigned _hi = umax_u(a, bq); a = _lo; bq = _hi; } while (0)
        #define MERGE_EPI(T, TP)                                           \
            do {                                                           \
                unsigned m0 = umin_u(k##T##0, __shfl_xor(k##T##7, 32, 64));\
                unsigned m1 = umin_u(k##T##1, __shfl_xor(k##T##6, 32, 64));\
                unsigned m2 = umin_u(k##T##2, __shfl_xor(k##T##5, 32, 64));\
                unsigned m3 = umin_u(k##T##3, __shfl_xor(k##T##4, 32, 64));\
                unsigned m4 = umin_u(k##T##4, __shfl_xor(k##T##3, 32, 64));\
                unsigned m5 = umin_u(k##T##5, __shfl_xor(k##T##2, 32, 64));\
                unsigned m6 = umin_u(k##T##6, __shfl_xor(k##T##1, 32, 64));\
                unsigned m7 = umin_u(k##T##7, __shfl_xor(k##T##0, 32, 64));\
                CEX(m0, m4); CEX(m1, m5); CEX(m2, m6); CEX(m3, m7);        \
                CEX(m0, m2); CEX(m1, m3); CEX(m4, m6); CEX(m5, m7);        \
                CEX(m0, m1); CEX(m2, m3); CEX(m4, m5); CEX(m6, m7);        \
                unsigned f0 = umin_u(m0, __shfl_xor(m7, 16, 64));          \
                unsigned f1 = umin_u(m1, __shfl_xor(m6, 16, 64));          \
                unsigned f2 = umin_u(m2, __shfl_xor(m5, 16, 64));          \
                unsigned f3 = umin_u(m3, __shfl_xor(m4, 16, 64));          \
                unsigned f4 = umin_u(m4, __shfl_xor(m3, 16, 64));          \
                unsigned f5 = umin_u(m5, __shfl_xor(m2, 16, 64));          \
                unsigned f6 = umin_u(m6, __shfl_xor(m1, 16, 64));          \
                unsigned f7 = umin_u(m7, __shfl_xor(m0, 16, 64));          \
                uint2 th = *(const uint2*)((TP) + 2 * g);                  \
                uint2 tl = *(const uint2*)((TP) + 8 + 2 * g);              \
                float tfa = uasf(th.x << 16)         + uasf(tl.x << 16);   \
                float tfb = uasf(th.x & 0xFFFF0000u) + uasf(tl.x & 0xFFFF0000u); \
                float tfc = uasf(th.y << 16)         + uasf(tl.y << 16);   \
                float tfd = uasf(th.y & 0xFFFF0000u) + uasf(tl.y & 0xFFFF0000u); \
                f32x4 uc4 = *(const f32x4*)&ucS[g4];                       \
                f32x4 wo4 = *(const f32x4*)&WoS[g4];                       \
                float part = (g == 0) ? ucS[HH] : 0.0f;                    \
                part = fmaf(tfa, uc4.x, part);                             \
                part = fmaf(tfb, uc4.y, part);                             \
                part = fmaf(tfc, uc4.z, part);                             \
                part = fmaf(tfd, uc4.w, part);                             \
                f32x4 mx = {-INFINITY, -INFINITY, -INFINITY, -INFINITY};   \
                mx = __builtin_elementwise_max(mx, *(const f32x4*)&proj[f0 & 127u][g4]); \
                mx = __builtin_elementwise_max(mx, *(const f32x4*)&proj[f1 & 127u][g4]); \
                mx = __builtin_elementwise_max(mx, *(const f32x4*)&proj[f2 & 127u][g4]); \
                mx = __builtin_elementwise_max(mx, *(const f32x4*)&proj[f3 & 127u][g4]); \
                mx = __builtin_elementwise_max(mx, *(const f32x4*)&proj[f4 & 127u][g4]); \
                mx = __builtin_elementwise_max(mx, *(const f32x4*)&proj[f5 & 127u][g4]); \
                mx = __builtin_elementwise_max(mx, *(const f32x4*)&proj[f6 & 127u][g4]); \
                mx = __builtin_elementwise_max(mx, *(const f32x4*)&proj[f7 & 127u][g4]); \
                part = fmaf(mx.x, wo4.x, part);                            \
                part = fmaf(mx.y, wo4.y, part);                            \
                part = fmaf(mx.z, wo4.z, part);                            \
                part = fmaf(mx.w, wo4.w, part);                            \
                part += __shfl_xor(part, 16, 64);                          \
                part += __shfl_xor(part, 32, 64);                          \
                float sg = __builtin_amdgcn_rcpf(1.0f + __builtin_amdgcn_exp2f(part * -1.44269504088896341f)); \
                if (g == 0) wsum += sg;                                    \
            } while (0)

        MERGE_EPI(0, tp0);
        MERGE_EPI(1, tp1);
        #undef MERGE_EPI
        #undef CEX
    }

    // ---- block mean-pool (g!=0 lanes contribute zero) ----
    #pragma unroll
    for (int off = 32; off > 0; off >>= 1)
        wsum += __shfl_down(wsum, off, 64);
    if ((tid & 63) == 0) sred[tid >> 6] = wsum;
    __syncthreads();
    if (tid == 0) {
        float tot = 0.0f;
        #pragma unroll
        for (int w2 = 0; w2 < TPB / 64; ++w2) tot += sred[w2];
        out[b]      = tot * (1.0f / NTRK);
        out[BB + b] = (float)b;
    }
}

extern "C" void kernel_launch(void* const* d_in, const int* in_sizes, int n_in,
                              void* d_out, int out_size, void* d_ws, size_t ws_size,
                              hipStream_t stream) {
    const float* x_sv  = (const float*)d_in[0];
    const float* x_trk = (const float*)d_in[1];
    const float* W1s = (const float*)d_in[4];
    const float* b1s = (const float*)d_in[5];
    const float* W2s = (const float*)d_in[6];
    const float* b2s = (const float*)d_in[7];
    const float* W1t = (const float*)d_in[8];
    const float* b1t = (const float*)d_in[9];
    const float* W2t = (const float*)d_in[10];
    const float* b2t = (const float*)d_in[11];
    const float* We  = (const float*)d_in[12];
    const float* be  = (const float*)d_in[13];
    const float* Wo  = (const float*)d_in[14];
    const float* bo  = (const float*)d_in[15];
    float* out = (float*)d_out;

    fused_all<<<BB, TPB, 0, stream>>>(x_sv, x_trk,
                                      W1s, b1s, W2s, b2s,
                                      W1t, b1t, W2t, b2t,
                                      We, be, Wo, bo,
                                      out);
}

// Round 10
// 109.705 us; speedup vs baseline: 1.2591x; 1.0501x over previous
//
#include <hip/hip_runtime.h>
#include <cmath>

#define BB   512
#define NSV  128
#define NTRK 512
#define KK   8
#define HH   16
#define TPB  1024          // 16 waves; threads 0-511 track MLP, 512-639 SV MLP (parallel)
#define TST  36            // T row stride in shorts (72B): [thi 16][tlo 16][htsq f32]  18 dwords, gcd(18,32)=2
#define SST  36            // S row stride in shorts: [shi 16][slo 16][pad]
#define PSTR 20            // proj stride (f32)

typedef float    vf2    __attribute__((ext_vector_type(2)));
typedef float    f32x4  __attribute__((ext_vector_type(4)));
typedef short    bf16x8 __attribute__((ext_vector_type(8)));
typedef unsigned u32x4  __attribute__((ext_vector_type(4)));

__device__ __forceinline__ float elu_f(float x) {
    float e = __builtin_amdgcn_exp2f(x * 1.44269504088896341f) - 1.0f;
    return x > 0.0f ? x : e;
}
__device__ __forceinline__ unsigned umin_u(unsigned a, unsigned b) { return a < b ? a : b; }
__device__ __forceinline__ unsigned umax_u(unsigned a, unsigned b) { return a > b ? a : b; }
__device__ __forceinline__ unsigned med3u(unsigned a, unsigned b, unsigned c) {
    unsigned d;
    asm("v_med3_u32 %0, %1, %2, %3" : "=v"(d) : "v"(a), "v"(b), "v"(c));
    return d;
}
__device__ __forceinline__ bf16x8 mk_bf8(uint2 a, uint2 b) {
    u32x4 u; u.x = a.x; u.y = a.y; u.z = b.x; u.w = b.y;
    return __builtin_bit_cast(bf16x8, u);
}
__device__ __forceinline__ float uasf(unsigned u) { return __uint_as_float(u); }

// One block = one batch. 1024 threads, 16 waves (8 waves/SIMD at 2 blocks/CU).
// R10 changes vs R9:
//  (1) ALL MLP loops reordered weight-ROW-major with vf2 accumulator arrays.
//      R9 iterated column-major (W[h*16+h2], h2 outer) -> ~500 scattered
//      stride-64B s_load_dword per thread with out-of-order lgkmcnt drains
//      (the R1 pathology relocated into phase A). Row-major streams rows as
//      contiguous s_load_dwordx4+ batches; vf2 math -> v_pk_fma_f32.
//  (2) C-init fold: MFMA C initialized to -(htsq+hq) so e = fmax(-acc, 0)
//      is one VOP (neg modifier); saves 2 VALU x 64 candidates/thread.
// [R9: TLP 4->8 waves/SIMD, 41.8 -> ~33us. R6 errata: 64 persistent frag
//  VGPRs spilled. R5: gcd-4 LDS strides. R4: ds_read broadcast rows 61us.
//  R1: SMEM ooo drains. R2/R3: private-array scratch.]
__global__ __launch_bounds__(TPB, 8) void fused_all(
    const float* __restrict__ x_sv, const float* __restrict__ x_trk,
    const float* __restrict__ W1s, const float* __restrict__ b1s,
    const float* __restrict__ W2s, const float* __restrict__ b2s,
    const float* __restrict__ W1t, const float* __restrict__ b1t,
    const float* __restrict__ W2t, const float* __restrict__ b2t,
    const float* __restrict__ We,  const float* __restrict__ be,
    const float* __restrict__ Wo,  const float* __restrict__ bo,
    float* __restrict__ out)
{
    __shared__ __align__(16) short Tsh[NTRK * TST];   // 36.9 KB
    __shared__ __align__(16) short Ssh[NSV * SST];    // 9.2 KB
    __shared__ __align__(16) float hsqS[NSV];         // 0.5 KB
    __shared__ __align__(16) float proj[NSV][PSTR];   // 10.2 KB
    __shared__ __align__(16) float ucS[HH + 1];
    __shared__ __align__(16) float WoS[HH];
    __shared__ float sred[TPB / 64];

    const int b = blockIdx.x, tid = threadIdx.x;

    // ================= phase A (parallel thread ranges) =================
    if (tid < NTRK) {
        // track MLP, row-major weight streaming
        const float* xp = x_trk + (size_t)(b * NTRK + tid) * 8;
        float x[8];
        *(float4*)&x[0] = *(const float4*)&xp[0];
        *(float4*)&x[4] = *(const float4*)&xp[4];
        vf2 h1[8];
        #pragma unroll
        for (int j = 0; j < 8; ++j) h1[j] = *(const vf2*)&b1t[2 * j];
        #pragma unroll
        for (int i = 0; i < 8; ++i) {
            vf2 xv = {x[i], x[i]};
            #pragma unroll
            for (int j = 0; j < 8; ++j)
                h1[j] = __builtin_elementwise_fma(xv, *(const vf2*)&W1t[i * HH + 2 * j], h1[j]);
        }
        float hb[HH];
        #pragma unroll
        for (int j = 0; j < 8; ++j) { hb[2 * j] = elu_f(h1[j].x); hb[2 * j + 1] = elu_f(h1[j].y); }
        vf2 t2[8];
        #pragma unroll
        for (int j = 0; j < 8; ++j) t2[j] = *(const vf2*)&b2t[2 * j];
        #pragma unroll
        for (int h = 0; h < HH; ++h) {
            vf2 hv = {hb[h], hb[h]};
            #pragma unroll
            for (int j = 0; j < 8; ++j)
                t2[j] = __builtin_elementwise_fma(hv, *(const vf2*)&W2t[h * HH + 2 * j], t2[j]);
        }
        float sq = 0.0f;
        #pragma unroll
        for (int j = 0; j < 8; ++j) {
            sq = fmaf(t2[j].x, t2[j].x, sq);
            sq = fmaf(t2[j].y, t2[j].y, sq);
        }
        unsigned hw[8], lw[8];
        #pragma unroll
        for (int j = 0; j < 8; ++j) {
            float f0 = t2[j].x, f1 = t2[j].y;
            unsigned u0 = __float_as_uint(f0) & 0xFFFF0000u;
            unsigned u1 = __float_as_uint(f1) & 0xFFFF0000u;
            hw[j] = (u0 >> 16) | u1;
            float r0 = f0 - uasf(u0);
            float r1 = f1 - uasf(u1);
            lw[j] = (__float_as_uint(r0) >> 16) | (__float_as_uint(r1) & 0xFFFF0000u);
        }
        unsigned* tr = (unsigned*)&Tsh[tid * TST];
        *(uint2*)(tr + 0)  = make_uint2(hw[0], hw[1]);
        *(uint2*)(tr + 2)  = make_uint2(hw[2], hw[3]);
        *(uint2*)(tr + 4)  = make_uint2(hw[4], hw[5]);
        *(uint2*)(tr + 6)  = make_uint2(hw[6], hw[7]);
        *(uint2*)(tr + 8)  = make_uint2(lw[0], lw[1]);
        *(uint2*)(tr + 10) = make_uint2(lw[2], lw[3]);
        *(uint2*)(tr + 12) = make_uint2(lw[4], lw[5]);
        *(uint2*)(tr + 14) = make_uint2(lw[6], lw[7]);
        ((float*)tr)[16] = 0.5f * sq;
    } else if (tid < NTRK + NSV) {
        const int s = tid - NTRK;
        const float* xp = x_sv + (size_t)(b * NSV + s) * 2;
        float x0 = xp[0], x1 = xp[1];
        vf2 s1[8];
        #pragma unroll
        for (int j = 0; j < 8; ++j) s1[j] = *(const vf2*)&b1s[2 * j];
        {
            vf2 x0v = {x0, x0}, x1v = {x1, x1};
            #pragma unroll
            for (int j = 0; j < 8; ++j)
                s1[j] = __builtin_elementwise_fma(x0v, *(const vf2*)&W1s[2 * j], s1[j]);
            #pragma unroll
            for (int j = 0; j < 8; ++j)
                s1[j] = __builtin_elementwise_fma(x1v, *(const vf2*)&W1s[HH + 2 * j], s1[j]);
        }
        float hb[HH];
        #pragma unroll
        for (int j = 0; j < 8; ++j) { hb[2 * j] = elu_f(s1[j].x); hb[2 * j + 1] = elu_f(s1[j].y); }
        vf2 t2[8];
        #pragma unroll
        for (int j = 0; j < 8; ++j) t2[j] = *(const vf2*)&b2s[2 * j];
        #pragma unroll
        for (int h = 0; h < HH; ++h) {
            vf2 hv = {hb[h], hb[h]};
            #pragma unroll
            for (int j = 0; j < 8; ++j)
                t2[j] = __builtin_elementwise_fma(hv, *(const vf2*)&W2s[h * HH + 2 * j], t2[j]);
        }
        float o[HH];
        float sq = 0.0f;
        #pragma unroll
        for (int j = 0; j < 8; ++j) {
            o[2 * j] = t2[j].x; o[2 * j + 1] = t2[j].y;
            sq = fmaf(t2[j].x, t2[j].x, sq);
            sq = fmaf(t2[j].y, t2[j].y, sq);
        }
        unsigned hw[8], lw[8];
        #pragma unroll
        for (int j = 0; j < 8; ++j) {
            float f0 = t2[j].x, f1 = t2[j].y;
            unsigned u0 = __float_as_uint(f0) & 0xFFFF0000u;
            unsigned u1 = __float_as_uint(f1) & 0xFFFF0000u;
            hw[j] = (u0 >> 16) | u1;
            float r0 = f0 - uasf(u0);
            float r1 = f1 - uasf(u1);
            lw[j] = (__float_as_uint(r0) >> 16) | (__float_as_uint(r1) & 0xFFFF0000u);
        }
        unsigned* sr = (unsigned*)&Ssh[s * SST];
        *(uint2*)(sr + 0)  = make_uint2(hw[0], hw[1]);
        *(uint2*)(sr + 2)  = make_uint2(hw[2], hw[3]);
        *(uint2*)(sr + 4)  = make_uint2(hw[4], hw[5]);
        *(uint2*)(sr + 6)  = make_uint2(hw[6], hw[7]);
        *(uint2*)(sr + 8)  = make_uint2(lw[0], lw[1]);
        *(uint2*)(sr + 10) = make_uint2(lw[2], lw[3]);
        *(uint2*)(sr + 12) = make_uint2(lw[4], lw[5]);
        *(uint2*)(sr + 14) = make_uint2(lw[6], lw[7]);
        hsqS[s] = 0.5f * sq;
        // proj = o @ We[16:32,:], row-major streaming over We rows
        vf2 p[8];
        #pragma unroll
        for (int m = 0; m < 8; ++m) p[m] = (vf2){0.0f, 0.0f};
        #pragma unroll
        for (int j = 0; j < HH; ++j) {
            vf2 ov = {o[j], o[j]};
            #pragma unroll
            for (int m = 0; m < 8; ++m)
                p[m] = __builtin_elementwise_fma(ov, *(const vf2*)&We[(HH + j) * HH + 2 * m], p[m]);
        }
        #pragma unroll
        for (int m = 0; m < 8; ++m)
            *(vf2*)&proj[s][2 * m] = p[m];
    } else if (tid < NTRK + NSV + HH) {
        int j = tid - NTRK - NSV;
        float a = 0.0f;
        #pragma unroll
        for (int h = 0; h < HH; ++h)
            a += (We[j * HH + h] - We[(HH + j) * HH + h]) * Wo[h];
        ucS[j] = a;
    } else if (tid < NTRK + NSV + 2 * HH) {
        int j = tid - NTRK - NSV - HH;
        WoS[j] = Wo[j];
    } else if (tid == NTRK + NSV + 2 * HH) {
        float a = bo[0];
        #pragma unroll
        for (int h = 0; h < HH; ++h) a += be[h] * Wo[h];
        ucS[HH] = a;
    }

    __syncthreads();

    // ================= phase B: MFMA + top-8 + fused epilogue =================
    float wsum = 0.0f;
    {
        const int lane = tid & 63;
        const int w    = tid >> 6;        // wave 0..15
        const int c    = lane & 15;
        const int g    = lane >> 4;
        const int g4   = g << 2;
        const int gd   = (g & 1) << 2;    // A-frag dword offset (dup-K)

        // hoist the 2 track B-frags + (-htsq) (8+2 VGPR persistent)
        const unsigned* tp0 = (const unsigned*)&Tsh[((w     ) * 16 + c) * TST];
        const unsigned* tp1 = (const unsigned*)&Tsh[((w + 16) * 16 + c) * TST];
        bf16x8 bf0 = mk_bf8(*(const uint2*)(tp0 + g * 4), *(const uint2*)(tp0 + g * 4 + 2));
        bf16x8 bf1 = mk_bf8(*(const uint2*)(tp1 + g * 4), *(const uint2*)(tp1 + g * 4 + 2));
        const float mht0 = -((const float*)tp0)[16];
        const float mht1 = -((const float*)tp1)[16];

        // per-tile selection state: 16 named regs
        unsigned k00=~0u,k01=~0u,k02=~0u,k03=~0u,k04=~0u,k05=~0u,k06=~0u,k07=~0u;
        unsigned k10=~0u,k11=~0u,k12=~0u,k13=~0u,k14=~0u,k15=~0u,k16=~0u,k17=~0u;

        #define CHAIN(v,K0,K1,K2,K3,K4,K5,K6,K7)                           \
            do {                                                           \
                unsigned nk0 = umin_u(v, K0);                              \
                unsigned nk1 = med3u(v, K0, K1);                           \
                unsigned nk2 = med3u(v, K1, K2);                           \
                unsigned nk3 = med3u(v, K2, K3);                           \
                unsigned nk4 = med3u(v, K3, K4);                           \
                unsigned nk5 = med3u(v, K4, K5);                           \
                unsigned nk6 = med3u(v, K5, K6);                           \
                unsigned nk7 = med3u(v, K6, K7);                           \
                K0 = nk0; K1 = nk1; K2 = nk2; K3 = nk3;                    \
                K4 = nk4; K5 = nk5; K6 = nk6; K7 = nk7;                    \
            } while (0)

        // C was initialized to -(htsq+hq): acc = dot - htsq - hq = -e.
        #define CONSUME(T, accv)                                           \
            do {                                                           \
                float e0 = fmaxf(-accv.x, 0.0f);                           \
                float e1 = fmaxf(-accv.y, 0.0f);                           \
                float e2 = fmaxf(-accv.z, 0.0f);                           \
                float e3 = fmaxf(-accv.w, 0.0f);                           \
                unsigned v0 = (__float_as_uint(e0) & 0xFFFFFF80u) | (unsigned)(sbase + 0); \
                CHAIN(v0,k##T##0,k##T##1,k##T##2,k##T##3,k##T##4,k##T##5,k##T##6,k##T##7); \
                unsigned v1 = (__float_as_uint(e1) & 0xFFFFFF80u) | (unsigned)(sbase + 1); \
                CHAIN(v1,k##T##0,k##T##1,k##T##2,k##T##3,k##T##4,k##T##5,k##T##6,k##T##7); \
                unsigned v2 = (__float_as_uint(e2) & 0xFFFFFF80u) | (unsigned)(sbase + 2); \
                CHAIN(v2,k##T##0,k##T##1,k##T##2,k##T##3,k##T##4,k##T##5,k##T##6,k##T##7); \
                unsigned v3 = (__float_as_uint(e3) & 0xFFFFFF80u) | (unsigned)(sbase + 3); \
                CHAIN(v3,k##T##0,k##T##1,k##T##2,k##T##3,k##T##4,k##T##5,k##T##6,k##T##7); \
            } while (0)

        #pragma unroll
        for (int ss = 0; ss < 8; ++ss) {
            const unsigned* sp = (const unsigned*)&Ssh[(ss * 16 + c) * SST];
            bf16x8 ah = mk_bf8(*(const uint2*)(sp + gd), *(const uint2*)(sp + gd + 2));
            bf16x8 al = mk_bf8(*(const uint2*)(sp + 8 + gd), *(const uint2*)(sp + 8 + gd + 2));
            f32x4 hq = *(const f32x4*)&hsqS[ss * 16 + g4];
            const int sbase = ss * 16 + g4;
            f32x4 ci0 = { mht0 - hq.x, mht0 - hq.y, mht0 - hq.z, mht0 - hq.w };
            f32x4 ci1 = { mht1 - hq.x, mht1 - hq.y, mht1 - hq.z, mht1 - hq.w };
            f32x4 a0 = __builtin_amdgcn_mfma_f32_16x16x32_bf16(ah, bf0, ci0, 0, 0, 0);
            f32x4 a1 = __builtin_amdgcn_mfma_f32_16x16x32_bf16(ah, bf1, ci1, 0, 0, 0);
            a0 = __builtin_amdgcn_mfma_f32_16x16x32_bf16(al, bf0, a0, 0, 0, 0);
            a1 = __builtin_amdgcn_mfma_f32_16x16x32_bf16(al, bf1, a1, 0, 0, 0);
            CONSUME(0, a0);
            CONSUME(1, a1);
        }
        #undef CONSUME
        #undef CHAIN

        // ---- per tile: merge 4 disjoint g-lane sets + fused epilogue ----
        #define CEX(a, bq) do { unsigned _lo = umin_u(a, bq); unsigned _hi = umax_u(a, bq); a = _lo; bq = _hi; } while (0)
        #define MERGE_EPI(T, TP)                                           \
            do {                                                           \
                unsigned m0 = umin_u(k##T##0, __shfl_xor(k##T##7, 32, 64));\
                unsigned m1 = umin_u(k##T##1, __shfl_xor(k##T##6, 32, 64));\
                unsigned m2 = umin_u(k##T##2, __shfl_xor(k##T##5, 32, 64));\
                unsigned m3 = umin_u(k##T##3, __shfl_xor(k##T##4, 32, 64));\
                unsigned m4 = umin_u(k##T##4, __shfl_xor(k##T##3, 32, 64));\
                unsigned m5 = umin_u(k##T##5, __shfl_xor(k##T##2, 32, 64));\
                unsigned m6 = umin_u(k##T##6, __shfl_xor(k##T##1, 32, 64));\
                unsigned m7 = umin_u(k##T##7, __shfl_xor(k##T##0, 32, 64));\
                CEX(m0, m4); CEX(m1, m5); CEX(m2, m6); CEX(m3, m7);        \
                CEX(m0, m2); CEX(m1, m3); CEX(m4, m6); CEX(m5, m7);        \
                CEX(m0, m1); CEX(m2, m3); CEX(m4, m5); CEX(m6, m7);        \
                unsigned f0 = umin_u(m0, __shfl_xor(m7, 16, 64));          \
                unsigned f1 = umin_u(m1, __shfl_xor(m6, 16, 64));          \
                unsigned f2 = umin_u(m2, __shfl_xor(m5, 16, 64));          \
                unsigned f3 = umin_u(m3, __shfl_xor(m4, 16, 64));          \
                unsigned f4 = umin_u(m4, __shfl_xor(m3, 16, 64));          \
                unsigned f5 = umin_u(m5, __shfl_xor(m2, 16, 64));          \
                unsigned f6 = umin_u(m6, __shfl_xor(m1, 16, 64));          \
                unsigned f7 = umin_u(m7, __shfl_xor(m0, 16, 64));          \
                uint2 th = *(const uint2*)((TP) + 2 * g);                  \
                uint2 tl = *(const uint2*)((TP) + 8 + 2 * g);              \
                float tfa = uasf(th.x << 16)         + uasf(tl.x << 16);   \
                float tfb = uasf(th.x & 0xFFFF0000u) + uasf(tl.x & 0xFFFF0000u); \
                float tfc = uasf(th.y << 16)         + uasf(tl.y << 16);   \
                float tfd = uasf(th.y & 0xFFFF0000u) + uasf(tl.y & 0xFFFF0000u); \
                f32x4 uc4 = *(const f32x4*)&ucS[g4];                       \
                f32x4 wo4 = *(const f32x4*)&WoS[g4];                       \
                float part = (g == 0) ? ucS[HH] : 0.0f;                    \
                part = fmaf(tfa, uc4.x, part);                             \
                part = fmaf(tfb, uc4.y, part);                             \
                part = fmaf(tfc, uc4.z, part);                             \
                part = fmaf(tfd, uc4.w, part);                             \
                f32x4 mx = {-INFINITY, -INFINITY, -INFINITY, -INFINITY};   \
                mx = __builtin_elementwise_max(mx, *(const f32x4*)&proj[f0 & 127u][g4]); \
                mx = __builtin_elementwise_max(mx, *(const f32x4*)&proj[f1 & 127u][g4]); \
                mx = __builtin_elementwise_max(mx, *(const f32x4*)&proj[f2 & 127u][g4]); \
                mx = __builtin_elementwise_max(mx, *(const f32x4*)&proj[f3 & 127u][g4]); \
                mx = __builtin_elementwise_max(mx, *(const f32x4*)&proj[f4 & 127u][g4]); \
                mx = __builtin_elementwise_max(mx, *(const f32x4*)&proj[f5 & 127u][g4]); \
                mx = __builtin_elementwise_max(mx, *(const f32x4*)&proj[f6 & 127u][g4]); \
                mx = __builtin_elementwise_max(mx, *(const f32x4*)&proj[f7 & 127u][g4]); \
                part = fmaf(mx.x, wo4.x, part);                            \
                part = fmaf(mx.y, wo4.y, part);                            \
                part = fmaf(mx.z, wo4.z, part);                            \
                part = fmaf(mx.w, wo4.w, part);                            \
                part += __shfl_xor(part, 16, 64);                          \
                part += __shfl_xor(part, 32, 64);                          \
                float sg = __builtin_amdgcn_rcpf(1.0f + __builtin_amdgcn_exp2f(part * -1.44269504088896341f)); \
                if (g == 0) wsum += sg;                                    \
            } while (0)

        MERGE_EPI(0, tp0);
        MERGE_EPI(1, tp1);
        #undef MERGE_EPI
        #undef CEX
    }

    // ---- block mean-pool (g!=0 lanes contribute zero) ----
    #pragma unroll
    for (int off = 32; off > 0; off >>= 1)
        wsum += __shfl_down(wsum, off, 64);
    if ((tid & 63) == 0) sred[tid >> 6] = wsum;
    __syncthreads();
    if (tid == 0) {
        float tot = 0.0f;
        #pragma unroll
        for (int w2 = 0; w2 < TPB / 64; ++w2) tot += sred[w2];
        out[b]      = tot * (1.0f / NTRK);
        out[BB + b] = (float)b;
    }
}

extern "C" void kernel_launch(void* const* d_in, const int* in_sizes, int n_in,
                              void* d_out, int out_size, void* d_ws, size_t ws_size,
                              hipStream_t stream) {
    const float* x_sv  = (const float*)d_in[0];
    const float* x_trk = (const float*)d_in[1];
    const float* W1s = (const float*)d_in[4];
    const float* b1s = (const float*)d_in[5];
    const float* W2s = (const float*)d_in[6];
    const float* b2s = (const float*)d_in[7];
    const float* W1t = (const float*)d_in[8];
    const float* b1t = (const float*)d_in[9];
    const float* W2t = (const float*)d_in[10];
    const float* b2t = (const float*)d_in[11];
    const float* We  = (const float*)d_in[12];
    const float* be  = (const float*)d_in[13];
    const float* Wo  = (const float*)d_in[14];
    const float* bo  = (const float*)d_in[15];
    float* out = (float*)d_out;

    fused_all<<<BB, TPB, 0, stream>>>(x_sv, x_trk,
                                      W1s, b1s, W2s, b2s,
                                      W1t, b1t, W2t, b2t,
                                      We, be, Wo, bo,
                                      out);
}